// Round 14
// baseline (84.105 us; speedup 1.0000x reference)
//
#include <hip/hip_runtime.h>

#define D        128
#define KCODES   2048
#define NROWS    32768
#define BATCH    8192

typedef _Float16 f16x8 __attribute__((ext_vector_type(8)));
typedef float    f32x4 __attribute__((ext_vector_type(4)));

#define MFMA16(a, b, c) __builtin_amdgcn_mfma_f32_16x16x32_f16((a), (b), (c), 0, 0, 0)
#define INV2048 4.8828125e-4f

static __device__ __forceinline__ void gload16(const void* g, void* l) {
    __builtin_amdgcn_global_load_lds(
        (const __attribute__((address_space(1))) unsigned int*)g,
        (__attribute__((address_space(3))) unsigned int*)l, 16, 0, 0);
}

// ---------------------------------------------------------------------------
// Kernel A: W -> (wh, wl) fp16 hi/lo in 16x16x32 fragment-linear layout +
// fp32 ||W||^2.  For 16-code tile n0, kstep ks, lane l holds
// W[n0*16 + (l&15)][ks*32 + (l>>4)*8 + j], at f16x8 idx ((n0*4+ks)*64+l).
// (verified by absmax 0 in R11-R13)
// ---------------------------------------------------------------------------
__global__ void wconv_kernel(const float* __restrict__ W,
                             _Float16* __restrict__ whf, _Float16* __restrict__ wlf,
                             float* __restrict__ wnorm) {
    int gid = blockIdx.x * 256 + threadIdx.x;    // 32768 = 2048 codes x 16 slots
    int n = gid >> 4, s = gid & 15;
    const float4* src = (const float4*)(W + (size_t)n * D + s * 8);
    float4 a = src[0], b = src[1];
    float va[8] = {a.x, a.y, a.z, a.w, b.x, b.y, b.z, b.w};
    f16x8 hi, lo;
    float ss = 0.0f;
#pragma unroll
    for (int j = 0; j < 8; ++j) {
        _Float16 h = (_Float16)va[j];
        hi[j] = h;
        lo[j] = (_Float16)((va[j] - (float)h) * 2048.0f);
        ss += va[j] * va[j];
    }
    size_t idx = ((size_t)((n >> 4) * 4 + (s >> 2)) * 64 + (s & 3) * 16 + (n & 15));
    ((f16x8*)whf)[idx] = hi;
    ((f16x8*)wlf)[idx] = lo;
#pragma unroll
    for (int m = 1; m <= 8; m <<= 1) ss += __shfl_xor(ss, m);
    if (s == 0) wnorm[n] = ss;
}

// ---------------------------------------------------------------------------
// Kernel A2: f -> (-2f) hi/lo fp16 in the same fragment-linear layout.
// ---------------------------------------------------------------------------
__global__ void fconv_kernel(const float* __restrict__ f,
                             _Float16* __restrict__ fhf, _Float16* __restrict__ flf) {
    int gid = blockIdx.x * 256 + threadIdx.x;    // 524288 = 32768 rows x 16 slots
    int n = gid >> 4, s = gid & 15;
    const float4* src = (const float4*)(f + (size_t)n * D + s * 8);
    float4 a = src[0], b = src[1];
    float va[8] = {a.x, a.y, a.z, a.w, b.x, b.y, b.z, b.w};
    f16x8 hi, lo;
#pragma unroll
    for (int j = 0; j < 8; ++j) {
        float x = -2.0f * va[j];
        _Float16 h = (_Float16)x;
        hi[j] = h;
        lo[j] = (_Float16)((x - (float)h) * 2048.0f);
    }
    size_t idx = ((size_t)((n >> 4) * 4 + (s >> 2)) * 64 + (s & 3) * 16 + (n & 15));
    ((f16x8*)fhf)[idx] = hi;
    ((f16x8*)flf)[idx] = lo;
}

// ---------------------------------------------------------------------------
// Kernel B: fused MFMA scores + argmin — rt=4 (64 rows/wave in regs) x ct=2
// (code-parity halves): 16 ds_read_b128 per 96 MFMA per chunk per wave.
// Grid 512 = 128 row-blocks(256 rows) x 4 code-quarters (XCD-pinned pairs).
// Block 512 thr = 8 waves = 4 wm (64 rows) x 2 p (parity).
// 8 chunks of 64 codes; 2 x 32KB LDS dbuf + 2KB wnorm = 66KB.
// A-frags pre-converted (fconv) -> coalesced 16B loads, no convert VALU.
// Serial-sum model: 7450(MFMA)+3072(LDS)+~1900(VALU) cyc/chunk/CU.
// ---------------------------------------------------------------------------
extern "C" __global__ void __launch_bounds__(512)
__attribute__((amdgpu_flat_work_group_size(512, 512)))
__attribute__((amdgpu_waves_per_eu(2, 2)))
vq_argmin(const _Float16* __restrict__ fhf, const _Float16* __restrict__ flf,
          const _Float16* __restrict__ whf, const _Float16* __restrict__ wlf,
          const float* __restrict__ wnorm,
          float* __restrict__ bsp, int* __restrict__ bcp) {
    extern __shared__ unsigned char lds[];   // [2][32768] dbuf | wnorm @65536

    const int b   = blockIdx.x;
    const int xcd = b & 7;
    const int qrt = xcd >> 1;                 // quarter 0..3 (2 XCDs each)
    const int rb  = (b >> 3) * 2 + (b & 1);   // row block 0..127 (256 rows)
    const int tid = threadIdx.x;
    const int w   = tid >> 6, l = tid & 63;
    const int wm  = w >> 1, p = w & 1;        // 64-row group / code parity
    const int l15 = l & 15, lq = l >> 4;

    const char* ghB = (const char*)whf + (size_t)qrt * 131072;
    const char* glB = (const char*)wlf + (size_t)qrt * 131072;

    // chunk c: 64 codes = 16KB hi + 16KB lo
#define STAGE(c) {                                                          \
        unsigned char* dB = lds + ((c) & 1) * 32768;                        \
        gload16(ghB + (size_t)(c) * 16384 + tid * 16,        dB + tid * 16);\
        gload16(ghB + (size_t)(c) * 16384 + 8192 + tid * 16, dB + 8192 + tid * 16);\
        gload16(glB + (size_t)(c) * 16384 + tid * 16,        dB + 16384 + tid * 16);\
        gload16(glB + (size_t)(c) * 16384 + 8192 + tid * 16, dB + 24576 + tid * 16);\
    }

    if (tid < 128)
        gload16((const char*)wnorm + qrt * 2048 + tid * 16, lds + 65536 + tid * 16);
    STAGE(0);

    // ---- A-fragments: 64 rows, pre-converted, coalesced 16B loads (128 VGPR) ----
    f16x8 fh[4][4], fl[4][4];
    {
        const f16x8* fhv = (const f16x8*)fhf;
        const f16x8* flv = (const f16x8*)flf;
        const int t0 = rb * 16 + wm * 4;      // row-tile base (16 rows/tile)
#pragma unroll
        for (int rt = 0; rt < 4; ++rt)
#pragma unroll
            for (int ks = 0; ks < 4; ++ks) {
                size_t idx = (size_t)((t0 + rt) * 4 + ks) * 64 + l;
                fh[rt][ks] = fhv[idx];
                fl[rt][ks] = flv[idx];
            }
    }

    __syncthreads();     // chunk 0 + wnorm staged (full vmcnt drain)

    const float* wnL = (const float*)(lds + 65536);

    float bestP[16];
#pragma unroll
    for (int e = 0; e < 16; ++e) bestP[e] = 3.4e38f;

#pragma unroll 1
    for (int t = 0; t < 8; ++t) {
        if (t > 0) {
            asm volatile("s_waitcnt vmcnt(0)" ::: "memory");
            __builtin_amdgcn_s_barrier();
            asm volatile("" ::: "memory");
        }
        if (t < 7) STAGE(t + 1);

        // wave's parity half: 2 tiles of 16 codes
        const unsigned char* wbh = lds + (t & 1) * 32768 + p * 8192;
        const unsigned char* wbl = wbh + 16384;

        float wv[2];
#pragma unroll
        for (int ct = 0; ct < 2; ++ct) wv[ct] = wnL[t * 64 + p * 32 + ct * 16 + l15];

        f32x4 accC[4][2], accH[4][2];
#pragma unroll
        for (int rt = 0; rt < 4; ++rt)
#pragma unroll
            for (int ct = 0; ct < 2; ++ct)
#pragma unroll
                for (int r = 0; r < 4; ++r) { accC[rt][ct][r] = 0.0f; accH[rt][ct][r] = wv[ct]; }

#pragma unroll
        for (int ks = 0; ks < 4; ++ks) {
            f16x8 wh[2], wl[2];
#pragma unroll
            for (int ct = 0; ct < 2; ++ct) {
                wh[ct] = *(const f16x8*)(wbh + ct * 4096 + ks * 1024 + l * 16);
                wl[ct] = *(const f16x8*)(wbl + ct * 4096 + ks * 1024 + l * 16);
            }
            __builtin_amdgcn_s_setprio(1);
            // 24 MFMAs, 16 chains, same-chain gap 8
#pragma unroll
            for (int ct = 0; ct < 2; ++ct)
#pragma unroll
                for (int rt = 0; rt < 4; ++rt)
                    accC[rt][ct] = MFMA16(fh[rt][ks], wl[ct], accC[rt][ct]);
#pragma unroll
            for (int ct = 0; ct < 2; ++ct)
#pragma unroll
                for (int rt = 0; rt < 4; ++rt)
                    accH[rt][ct] = MFMA16(fh[rt][ks], wh[ct], accH[rt][ct]);
#pragma unroll
            for (int ct = 0; ct < 2; ++ct)
#pragma unroll
                for (int rt = 0; rt < 4; ++rt)
                    accC[rt][ct] = MFMA16(fl[rt][ks], wh[ct], accC[rt][ct]);
            __builtin_amdgcn_s_setprio(0);
        }

        // ---- fold: s = accH + accC/2048; meta = t*2+ct in low 4 bits ----
#pragma unroll
        for (int ct = 0; ct < 2; ++ct) {
            const unsigned mv = (unsigned)(t * 2 + ct);
#pragma unroll
            for (int rt = 0; rt < 4; ++rt)
#pragma unroll
                for (int r = 0; r < 4; ++r) {
                    float s = fmaf(accC[rt][ct][r], INV2048, accH[rt][ct][r]);
                    unsigned pk = (__float_as_uint(s) & 0xFFFFFFF0u) | mv;
                    const int e = rt * 4 + r;
                    bestP[e] = fminf(bestP[e], __uint_as_float(pk));
                }
        }
    }
#undef STAGE

    // ---- butterfly over 16 code-cols; parity partials -> LDS merge ----
    __syncthreads();
    float* redS = (float*)lds;                   // [2][256]
    int*   redC = (int*)(lds + 2048);            // [2][256]
#pragma unroll
    for (int e = 0; e < 16; ++e) {
        const int rt = e >> 2, r = e & 3;
        float s = bestP[e];
        unsigned m = __float_as_uint(s) & 15u;
        // code = qrt*512 + t*64 + p*32 + ct*16 + col
        int c = qrt * 512 + (int)(m >> 1) * 64 + p * 32 + (int)(m & 1) * 16 + l15;
#pragma unroll
        for (int msk = 1; msk <= 8; msk <<= 1) {
            float s2 = __shfl_xor(s, msk);
            int   c2 = __shfl_xor(c, msk);
            if (s2 < s || (s2 == s && c2 < c)) { s = s2; c = c2; }
        }
        if (l15 == 0) {
            int row = wm * 64 + rt * 16 + lq * 4 + r;    // block-local 0..255
            redS[p * 256 + row] = s;
            redC[p * 256 + row] = c;
        }
    }
    __syncthreads();
    if (tid < 256) {
        float s0 = redS[tid], s1 = redS[256 + tid];
        int   c0 = redC[tid], c1 = redC[256 + tid];
        bool take1 = (s1 < s0) || (s1 == s0 && c1 < c0);
        bsp[(size_t)qrt * NROWS + rb * 256 + tid] = take1 ? s1 : s0;
        bcp[(size_t)qrt * NROWS + rb * 256 + tid] = take1 ? c1 : c0;
    }
}

// ---------------------------------------------------------------------------
// Kernel C: merge the 4 quarter partials, gather W[j], write out + loss.
// ---------------------------------------------------------------------------
__global__ void gather_kernel(const float* __restrict__ f, const float* __restrict__ W,
                              const float* __restrict__ bsp, const int* __restrict__ bcp,
                              float* __restrict__ loss, float* __restrict__ outv) {
    int b  = blockIdx.x;
    int wv = threadIdx.x >> 6;
    int l  = threadIdx.x & 63;
    int n  = b * 4 + wv;
    float s; int c;
    if (l < 4) { s = bsp[(size_t)l * NROWS + n]; c = bcp[(size_t)l * NROWS + n]; }
    else       { s = 3.4e38f; c = 0x7FFFFFFF; }
#pragma unroll
    for (int msk = 1; msk <= 2; msk <<= 1) {
        float s2 = __shfl_xor(s, msk);
        int   c2 = __shfl_xor(c, msk);
        if (s2 < s || (s2 == s && c2 < c)) { s = s2; c = c2; }
    }
    int j = __shfl(c, 0);
    float2 fv = reinterpret_cast<const float2*>(f + (size_t)n * D)[l];
    float2 wj = reinterpret_cast<const float2*>(W + (size_t)j * D)[l];
    reinterpret_cast<float2*>(outv + (size_t)n * D)[l] = wj;
    float dx = fv.x - wj.x, dy = fv.y - wj.y;
    float ls = dx * dx + dy * dy;
#pragma unroll
    for (int off = 32; off; off >>= 1) ls += __shfl_down(ls, off);
    __shared__ float lsm[4];
    if (l == 0) lsm[wv] = ls;
    __syncthreads();
    if (threadIdx.x == 0)
        loss[b] = 1.25f * 0.25f * (lsm[0] + lsm[1] + lsm[2] + lsm[3]);
}

// ---------------------------------------------------------------------------
extern "C" void kernel_launch(void* const* d_in, const int* in_sizes, int n_in,
                              void* d_out, int out_size, void* d_ws, size_t ws_size,
                              hipStream_t stream) {
    const float* f = (const float*)d_in[0];   // [8192,512] -> 32768 rows of 128
    const float* W = (const float*)d_in[1];   // [2048,128]

    float* loss = (float*)d_out;              // [8192]
    float* outv = (float*)d_out + BATCH;      // [8192*512]

    // fh/fl scratch lives in the outv region (16 MB, exact fit); fully
    // consumed by vq_argmin before gather_kernel overwrites outv.
    _Float16* fhf = (_Float16*)outv;                              // 8 MB
    _Float16* flf = (_Float16*)((char*)outv + 8388608);           // 8 MB

    // workspace layout
    float*    wnorm = (float*)d_ws;                              // @0       (8 KB)
    _Float16* whf   = (_Float16*)((char*)d_ws + 8192);           // @8K    (512 KB)
    _Float16* wlf   = (_Float16*)((char*)d_ws + 532480);         // @520K  (512 KB)
    float*    bsp   = (float*)((char*)d_ws + 1056768);           //        (512 KB)
    int*      bcp   = (int*)((char*)d_ws + 1581056);             //        (512 KB)

    wconv_kernel<<<KCODES * 16 / 256, 256, 0, stream>>>(W, whf, wlf, wnorm);
    fconv_kernel<<<NROWS * 16 / 256, 256, 0, stream>>>(f, fhf, flf);

    hipLaunchKernelGGL(vq_argmin, dim3(512), dim3(512), 67584, stream,
                       fhf, flf, whf, wlf, wnorm, bsp, bcp);

    gather_kernel<<<BATCH, 256, 0, stream>>>(f, W, bsp, bcp, loss, outv);
}

// Round 16
// 66.989 us; speedup vs baseline: 1.2555x; 1.2555x over previous
//
#include <hip/hip_runtime.h>

#define D        128
#define KCODES   2048
#define NROWS    32768
#define BATCH    8192

typedef _Float16 f16x8 __attribute__((ext_vector_type(8)));
typedef float    f32x4 __attribute__((ext_vector_type(4)));

#define MFMA16(a, b, c) __builtin_amdgcn_mfma_f32_16x16x32_f16((a), (b), (c), 0, 0, 0)
#define INV2048 4.8828125e-4f

static __device__ __forceinline__ void gload16(const void* g, void* l) {
    __builtin_amdgcn_global_load_lds(
        (const __attribute__((address_space(1))) unsigned int*)g,
        (__attribute__((address_space(3))) unsigned int*)l, 16, 0, 0);
}

// min-reduce a packed float across each 16-lane row via DPP row_ror (pure VALU)
static __device__ __forceinline__ float dppmin16(float s) {
    int t;
    t = __builtin_amdgcn_update_dpp(0, __float_as_int(s), 0x121, 0xf, 0xf, true);
    s = fminf(s, __int_as_float(t));
    t = __builtin_amdgcn_update_dpp(0, __float_as_int(s), 0x122, 0xf, 0xf, true);
    s = fminf(s, __int_as_float(t));
    t = __builtin_amdgcn_update_dpp(0, __float_as_int(s), 0x124, 0xf, 0xf, true);
    s = fminf(s, __int_as_float(t));
    t = __builtin_amdgcn_update_dpp(0, __float_as_int(s), 0x128, 0xf, 0xf, true);
    s = fminf(s, __int_as_float(t));
    return s;
}

// ---------------------------------------------------------------------------
// Kernel A: W -> (wh, wl) fp16 hi/lo in 16x16x32 fragment-linear layout +
// fp32 ||W||^2.  For 16-code tile n0, kstep ks, lane l holds
// W[n0*16 + (l&15)][ks*32 + (l>>4)*8 + j], at f16x8 idx ((n0*4+ks)*64+l).
// (verified by absmax 0 in R11-R14)
// ---------------------------------------------------------------------------
__global__ void wconv_kernel(const float* __restrict__ W,
                             _Float16* __restrict__ whf, _Float16* __restrict__ wlf,
                             float* __restrict__ wnorm) {
    int gid = blockIdx.x * 256 + threadIdx.x;    // 32768 = 2048 codes x 16 slots
    int n = gid >> 4, s = gid & 15;
    const float4* src = (const float4*)(W + (size_t)n * D + s * 8);
    float4 a = src[0], b = src[1];
    float va[8] = {a.x, a.y, a.z, a.w, b.x, b.y, b.z, b.w};
    f16x8 hi, lo;
    float ss = 0.0f;
#pragma unroll
    for (int j = 0; j < 8; ++j) {
        _Float16 h = (_Float16)va[j];
        hi[j] = h;
        lo[j] = (_Float16)((va[j] - (float)h) * 2048.0f);
        ss += va[j] * va[j];
    }
    size_t idx = ((size_t)((n >> 4) * 4 + (s >> 2)) * 64 + (s & 3) * 16 + (n & 15));
    ((f16x8*)whf)[idx] = hi;
    ((f16x8*)wlf)[idx] = lo;
#pragma unroll
    for (int m = 1; m <= 8; m <<= 1) ss += __shfl_xor(ss, m);
    if (s == 0) wnorm[n] = ss;
}

// ---------------------------------------------------------------------------
// Kernel A2: f -> (-2f) hi/lo fp16 in the same fragment-linear layout.
// ---------------------------------------------------------------------------
__global__ void fconv_kernel(const float* __restrict__ f,
                             _Float16* __restrict__ fhf, _Float16* __restrict__ flf) {
    int gid = blockIdx.x * 256 + threadIdx.x;    // 524288 = 32768 rows x 16 slots
    int n = gid >> 4, s = gid & 15;
    const float4* src = (const float4*)(f + (size_t)n * D + s * 8);
    float4 a = src[0], b = src[1];
    float va[8] = {a.x, a.y, a.z, a.w, b.x, b.y, b.z, b.w};
    f16x8 hi, lo;
#pragma unroll
    for (int j = 0; j < 8; ++j) {
        float x = -2.0f * va[j];
        _Float16 h = (_Float16)x;
        hi[j] = h;
        lo[j] = (_Float16)((x - (float)h) * 2048.0f);
    }
    size_t idx = ((size_t)((n >> 4) * 4 + (s >> 2)) * 64 + (s & 3) * 16 + (n & 15));
    ((f16x8*)fhf)[idx] = hi;
    ((f16x8*)flf)[idx] = lo;
}

// ---------------------------------------------------------------------------
// Kernel B: W-STATIONARY fused MFMA scores + argmin.
// Grid 256 = 64 row-groups(512 rows) x 4 code-blocks(512 codes); cb = b&3.
// Block 512 thr = 8 waves; wave w owns 64 codes (wh+wl in 128 VGPRs).
// f streams through LDS: 4 chunks x 128 rows (64KB, dbuf), staged once,
// read by all 8 waves -> LDS read volume HALVED vs f-stationary.
// Per 16-row tile per wave: 8 ds_read_b128 -> 48 MFMA (8 chains, gap 8).
// Argmin: pack (ct,col) into score low 6 bits, DPP row_ror min (VALU-only),
// one b128 merge write/tile into mrg[w][c*128 + tile-rows] (R15 bugfix).
// ---------------------------------------------------------------------------
extern "C" __global__ void __launch_bounds__(512)
__attribute__((amdgpu_flat_work_group_size(512, 512)))
__attribute__((amdgpu_waves_per_eu(2, 2)))
vq_argmin(const _Float16* __restrict__ fhf, const _Float16* __restrict__ flf,
          const _Float16* __restrict__ whf, const _Float16* __restrict__ wlf,
          const float* __restrict__ wnorm,
          float* __restrict__ bsp, int* __restrict__ bcp) {
    extern __shared__ unsigned char lds[];   // [2][65536] f dbuf | merge @131072 (16KB)

    const int b   = blockIdx.x;
    const int cb  = b & 3;                   // code block 0..3 (XCD-pinned)
    const int rg  = b >> 2;                  // row group 0..63 (512 rows)
    const int tid = threadIdx.x;
    const int w   = tid >> 6, l = tid & 63;
    const int l15 = l & 15, lq = l >> 4;

    const char* fhB = (const char*)fhf + (size_t)rg * 131072;   // 512 rows * 256B
    const char* flB = (const char*)flf + (size_t)rg * 131072;

    // chunk c: 128 rows = 8 tiles = 32KB hi + 32KB lo
#define STAGE(c) {                                                          \
        unsigned char* dB = lds + ((c) & 1) * 65536;                        \
        const char* sh = fhB + (size_t)(c) * 32768;                         \
        const char* sl = flB + (size_t)(c) * 32768;                         \
        gload16(sh + tid * 16,         dB + tid * 16);                      \
        gload16(sh + 8192  + tid * 16, dB + 8192  + tid * 16);              \
        gload16(sh + 16384 + tid * 16, dB + 16384 + tid * 16);              \
        gload16(sh + 24576 + tid * 16, dB + 24576 + tid * 16);              \
        gload16(sl + tid * 16,         dB + 32768 + tid * 16);              \
        gload16(sl + 8192  + tid * 16, dB + 40960 + tid * 16);              \
        gload16(sl + 16384 + tid * 16, dB + 49152 + tid * 16);              \
        gload16(sl + 24576 + tid * 16, dB + 57344 + tid * 16);              \
    }

    STAGE(0);

    // ---- W fragments: 64 codes (4 ct-tiles), hi+lo, in registers (128 VGPR) ----
    f16x8 wh[4][4], wl[4][4];
    {
        const f16x8* whv = (const f16x8*)whf;
        const f16x8* wlv = (const f16x8*)wlf;
        const int n0 = cb * 32 + w * 4;
#pragma unroll
        for (int ct = 0; ct < 4; ++ct)
#pragma unroll
            for (int ks = 0; ks < 4; ++ks) {
                size_t idx = (size_t)((n0 + ct) * 4 + ks) * 64 + l;
                wh[ct][ks] = whv[idx];
                wl[ct][ks] = wlv[idx];
            }
    }
    float wv[4];
    unsigned mv[4];
#pragma unroll
    for (int ct = 0; ct < 4; ++ct) {
        wv[ct] = wnorm[cb * 512 + w * 64 + ct * 16 + l15];
        mv[ct] = (unsigned)(ct << 4) | (unsigned)l15;
    }

    __syncthreads();     // chunk 0 staged; all reg loads complete

    float* mrg = (float*)(lds + 131072);     // [8 waves][512 rows] packed scores

#pragma unroll 1
    for (int c = 0; c < 4; ++c) {
        if (c < 3) STAGE(c + 1);
        const unsigned char* wb = lds + (c & 1) * 65536;

#pragma unroll 2
        for (int tl = 0; tl < 8; ++tl) {
            // A-frags for this 16-row tile (hi+lo), shared across 4 ct
            f16x8 fhk[4], flk[4];
#pragma unroll
            for (int ks = 0; ks < 4; ++ks) {
                fhk[ks] = *(const f16x8*)(wb + ((tl * 4 + ks) << 10) + l * 16);
                flk[ks] = *(const f16x8*)(wb + 32768 + ((tl * 4 + ks) << 10) + l * 16);
            }

            f32x4 accC[4], accH[4];
#pragma unroll
            for (int ct = 0; ct < 4; ++ct)
#pragma unroll
                for (int r = 0; r < 4; ++r) { accC[ct][r] = 0.0f; accH[ct][r] = wv[ct]; }

#pragma unroll
            for (int ks = 0; ks < 4; ++ks) {
                __builtin_amdgcn_s_setprio(1);
                // 12 MFMAs, 8 chains, same-chain gap 8
#pragma unroll
                for (int ct = 0; ct < 4; ++ct)
                    accC[ct] = MFMA16(fhk[ks], wl[ct][ks], accC[ct]);
#pragma unroll
                for (int ct = 0; ct < 4; ++ct)
                    accH[ct] = MFMA16(fhk[ks], wh[ct][ks], accH[ct]);
#pragma unroll
                for (int ct = 0; ct < 4; ++ct)
                    accC[ct] = MFMA16(flk[ks], wh[ct][ks], accC[ct]);
                __builtin_amdgcn_s_setprio(0);
            }

            // ---- fold: per row-slot r, min over 4 ct, (ct,col) in low 6 bits ----
            float bestR[4] = {3.4e38f, 3.4e38f, 3.4e38f, 3.4e38f};
#pragma unroll
            for (int ct = 0; ct < 4; ++ct)
#pragma unroll
                for (int r = 0; r < 4; ++r) {
                    float s = fmaf(accC[ct][r], INV2048, accH[ct][r]);
                    unsigned pk = (__float_as_uint(s) & 0xFFFFFFC0u) | mv[ct];
                    bestR[r] = fminf(bestR[r], __uint_as_float(pk));
                }
            // min over the 16 code-columns (DPP, VALU-only)
#pragma unroll
            for (int r = 0; r < 4; ++r) bestR[r] = dppmin16(bestR[r]);

            if (l15 == 0) {
                f32x4 v;
                v[0] = bestR[0]; v[1] = bestR[1]; v[2] = bestR[2]; v[3] = bestR[3];
                // block-local row = c*128 + tl*16 + lq*4 + [0..3]   (R15 FIX: +c*128)
                *(f32x4*)(mrg + w * 512 + c * 128 + tl * 16 + lq * 4) = v;
            }
        }
        asm volatile("s_waitcnt vmcnt(0)" ::: "memory");
        __builtin_amdgcn_s_barrier();
        asm volatile("" ::: "memory");
    }
#undef STAGE

    // ---- epilogue: merge 8 waves per row; decode packed meta -> code ----
    __syncthreads();
    {
        int row = tid;                        // 512 rows
        float s = mrg[row];
        int wBest = 0;
#pragma unroll
        for (int ww = 1; ww < 8; ++ww) {
            float s2 = mrg[ww * 512 + row];
            if (s2 < s) { s = s2; wBest = ww; }
        }
        unsigned bits = __float_as_uint(s);
        int code = cb * 512 + wBest * 64 + (int)((bits >> 4) & 3u) * 16 + (int)(bits & 15u);
        bsp[(size_t)cb * NROWS + rg * 512 + row] = s;
        bcp[(size_t)cb * NROWS + rg * 512 + row] = code;
    }
}

// ---------------------------------------------------------------------------
// Kernel C: merge the 4 code-block partials, gather W[j], write out + loss.
// ---------------------------------------------------------------------------
__global__ void gather_kernel(const float* __restrict__ f, const float* __restrict__ W,
                              const float* __restrict__ bsp, const int* __restrict__ bcp,
                              float* __restrict__ loss, float* __restrict__ outv) {
    int b  = blockIdx.x;
    int wv = threadIdx.x >> 6;
    int l  = threadIdx.x & 63;
    int n  = b * 4 + wv;
    float s; int c;
    if (l < 4) { s = bsp[(size_t)l * NROWS + n]; c = bcp[(size_t)l * NROWS + n]; }
    else       { s = 3.4e38f; c = 0x7FFFFFFF; }
#pragma unroll
    for (int msk = 1; msk <= 2; msk <<= 1) {
        float s2 = __shfl_xor(s, msk);
        int   c2 = __shfl_xor(c, msk);
        if (s2 < s || (s2 == s && c2 < c)) { s = s2; c = c2; }
    }
    int j = __shfl(c, 0);
    float2 fv = reinterpret_cast<const float2*>(f + (size_t)n * D)[l];
    float2 wj = reinterpret_cast<const float2*>(W + (size_t)j * D)[l];
    reinterpret_cast<float2*>(outv + (size_t)n * D)[l] = wj;
    float dx = fv.x - wj.x, dy = fv.y - wj.y;
    float ls = dx * dx + dy * dy;
#pragma unroll
    for (int off = 32; off; off >>= 1) ls += __shfl_down(ls, off);
    __shared__ float lsm[4];
    if (l == 0) lsm[wv] = ls;
    __syncthreads();
    if (threadIdx.x == 0)
        loss[b] = 1.25f * 0.25f * (lsm[0] + lsm[1] + lsm[2] + lsm[3]);
}

// ---------------------------------------------------------------------------
extern "C" void kernel_launch(void* const* d_in, const int* in_sizes, int n_in,
                              void* d_out, int out_size, void* d_ws, size_t ws_size,
                              hipStream_t stream) {
    const float* f = (const float*)d_in[0];   // [8192,512] -> 32768 rows of 128
    const float* W = (const float*)d_in[1];   // [2048,128]

    float* loss = (float*)d_out;              // [8192]
    float* outv = (float*)d_out + BATCH;      // [8192*512]

    // fh/fl scratch lives in the outv region (16 MB, exact fit); fully
    // consumed by vq_argmin before gather_kernel overwrites outv.
    _Float16* fhf = (_Float16*)outv;                              // 8 MB
    _Float16* flf = (_Float16*)((char*)outv + 8388608);           // 8 MB

    // workspace layout
    float*    wnorm = (float*)d_ws;                              // @0       (8 KB)
    _Float16* whf   = (_Float16*)((char*)d_ws + 8192);           // @8K    (512 KB)
    _Float16* wlf   = (_Float16*)((char*)d_ws + 532480);         // @520K  (512 KB)
    float*    bsp   = (float*)((char*)d_ws + 1056768);           //        (512 KB)
    int*      bcp   = (int*)((char*)d_ws + 1581056);             //        (512 KB)

    wconv_kernel<<<KCODES * 16 / 256, 256, 0, stream>>>(W, whf, wlf, wnorm);
    fconv_kernel<<<NROWS * 16 / 256, 256, 0, stream>>>(f, fhf, flf);

    hipLaunchKernelGGL(vq_argmin, dim3(256), dim3(512), 147456, stream,
                       fhf, flf, whf, wlf, wnorm, bsp, bcp);

    gather_kernel<<<BATCH, 256, 0, stream>>>(f, W, bsp, bcp, loss, outv);
}